// Round 1
// baseline (379.409 us; speedup 1.0000x reference)
//
#include <hip/hip_runtime.h>
#include <hip/hip_bf16.h>
#include <stdint.h>

typedef __bf16 bf16_t;
typedef __bf16 bf16x8 __attribute__((ext_vector_type(8)));
typedef float  f32x4  __attribute__((ext_vector_type(4)));

constexpr int kOH = 222, kOW = 222;
constexpr int kS   = kOH * kOW;        // 49284 pixels per (b) image
constexpr int kCin = 32, kH = 224, kW = 224;
constexpr int kCout = 64;
constexpr int kK   = 288;              // C_in * 9
constexpr int kB   = 16;
constexpr int kM   = kB * kS;          // 788544 output rows
constexpr int kBM  = 64;               // rows per block
constexpr int kLDK = 296;              // padded K stride (bf16 elems), mult of 8

// weights fp32 [288][64] -> ws bf16 [64][296] transposed + zero-padded
__global__ void prep_weights(const float* __restrict__ w, bf16_t* __restrict__ wt) {
    int e = blockIdx.x * 256 + threadIdx.x;
    if (e >= kCout * kLDK) return;
    int n = e / kLDK, f = e - n * kLDK;
    float v = (f < kK) ? w[f * kCout + n] : 0.0f;
    wt[e] = (bf16_t)v;
}

__global__ __launch_bounds__(256) void conv_mfma(
        const float* __restrict__ x, const bf16_t* __restrict__ wt,
        const float* __restrict__ bias, float* __restrict__ out) {
    __shared__ __align__(16) bf16_t sA[kBM * kLDK];   // X tile [64 rows][296]

    const int tid = threadIdx.x;
    const int m0  = blockIdx.x * kBM;

    // ---- stage expanded A tile: 2048 pix positions x 9 taps, bf16 ----
    #pragma unroll
    for (int it = 0; it < 8; ++it) {
        int pl = it * 256 + tid;           // pix_local in [0,2048)
        int r  = pl >> 5;                  // row within tile
        int t  = pl & 31;                  // t in [0,32)
        int m  = m0 + r;
        int b  = m / kS;                   // magic-mul div
        int s  = m - b * kS;
        int pix = s * 32 + t;
        int c  = pix / kS;
        int pp = pix - c * kS;
        int ii = pp / kOW;
        int jj = pp - ii * kOW;
        const float* xp = x + ((b * kCin + c) * kH + ii) * kW + jj;
        bf16_t* ap = sA + r * kLDK + t * 9;
        #pragma unroll
        for (int di = 0; di < 3; ++di)
            #pragma unroll
            for (int dj = 0; dj < 3; ++dj)
                ap[di * 3 + dj] = (bf16_t)xp[di * kW + dj];
    }

    // ---- each wave preloads its 16 weight rows as 9 A-fragments ----
    const int wv   = tid >> 6;        // wave 0..3 -> n-tile
    const int lane = tid & 63;
    const int lc   = lane & 15;
    const int q    = lane >> 4;

    bf16x8 afr[9];
    #pragma unroll
    for (int ks = 0; ks < 9; ++ks) {
        const bf16_t* p = wt + (wv * 16 + lc) * kLDK + ks * 32 + q * 8;
        afr[ks] = *(const bf16x8*)p;   // global, L2-hot (38 KB total)
    }

    __syncthreads();

    // ---- MFMA: D[n(16)][pix(16)] per pixel-group; A=weights, B=pixels ----
    f32x4 acc[4] = {};
    #pragma unroll
    for (int pg = 0; pg < 4; ++pg) {
        const bf16_t* bx = sA + (pg * 16 + lc) * kLDK;
        #pragma unroll
        for (int ks = 0; ks < 9; ++ks) {
            bf16x8 bfrag = *(const bf16x8*)(bx + ks * 32 + q * 8);
            acc[pg] = __builtin_amdgcn_mfma_f32_16x16x32_bf16(afr[ks], bfrag, acc[pg], 0, 0, 0);
        }
    }

    // ---- epilogue: col(lane&15)=pixel -> coalesced stores over s ----
    #pragma unroll
    for (int pg = 0; pg < 4; ++pg) {
        int m = m0 + pg * 16 + lc;
        int b = m / kS;
        int s = m - b * kS;
        float* op = out + (b * kCout) * kS + s;
        #pragma unroll
        for (int reg = 0; reg < 4; ++reg) {
            int n = wv * 16 + q * 4 + reg;
            op[n * kS] = acc[pg][reg] + bias[n];
        }
    }
}

extern "C" void kernel_launch(void* const* d_in, const int* in_sizes, int n_in,
                              void* d_out, int out_size, void* d_ws, size_t ws_size,
                              hipStream_t stream) {
    (void)in_sizes; (void)n_in; (void)out_size; (void)ws_size;
    const float* x    = (const float*)d_in[0];
    const float* w    = (const float*)d_in[1];
    const float* bias = (const float*)d_in[2];
    float*       out  = (float*)d_out;
    bf16_t*      wt   = (bf16_t*)d_ws;   // 64*296*2 = 37888 B

    prep_weights<<<(kCout * kLDK + 255) / 256, 256, 0, stream>>>(w, wt);
    conv_mfma<<<kM / kBM, 256, 0, stream>>>(x, wt, bias, out);
}